// Round 6
// baseline (286.058 us; speedup 1.0000x reference)
//
#include <hip/hip_runtime.h>
#include <math.h>

#define BB 256
#define SS 256
#define NH 4

typedef __attribute__((ext_vector_type(8))) short bfrag;   // 8 bf16 (4 VGPRs)
typedef __attribute__((ext_vector_type(4))) float ffrag;   // 4 fp32 acc

__device__ inline unsigned short f2bf(float x) {
    unsigned u = __float_as_uint(x);
    u += 0x7FFF + ((u >> 16) & 1);          // round-to-nearest-even
    return (unsigned short)(u >> 16);
}
__device__ inline float bf2f(unsigned short h) {
    return __uint_as_float(((unsigned)h) << 16);
}
__device__ inline unsigned pack2(float a, float b) {
    return (unsigned)f2bf(a) | ((unsigned)f2bf(b) << 16);
}
__device__ inline bfrag pack_frag(float4 a, float4 b) {
    bfrag f;
    f[0] = (short)f2bf(a.x); f[1] = (short)f2bf(a.y);
    f[2] = (short)f2bf(a.z); f[3] = (short)f2bf(a.w);
    f[4] = (short)f2bf(b.x); f[5] = (short)f2bf(b.y);
    f[6] = (short)f2bf(b.z); f[7] = (short)f2bf(b.w);
    return f;
}
union FragU { unsigned u[4]; bfrag b; };

// ws layout (bf16 elements): Wb [512][128] at 0, Wob [128][128] at 65536.
#define WB_OFF  0
#define WOB_OFF 65536

// ---------------------------------------------------------------------------
// k0: cast W_qkvg + W_o fp32 -> bf16. 81920 elems, 8/thread, 40 blocks.
// ---------------------------------------------------------------------------
__global__ __launch_bounds__(256) void k0_cast(
    const float* __restrict__ W, const float* __restrict__ Wo,
    unsigned short* __restrict__ dst)
{
    const int gid = blockIdx.x * 256 + threadIdx.x;
    const int WN8 = 65536 / 8, WoN8 = 16384 / 8;
    const float* src;
    size_t soff, doff;
    if (gid < WN8)            { src = W;  soff = (size_t)gid * 8;         doff = WB_OFF + soff; }
    else if (gid < WN8 + WoN8) { src = Wo; soff = (size_t)(gid - WN8) * 8; doff = WOB_OFF + soff; }
    else return;
    const float4 a = *(const float4*)(src + soff);
    const float4 b = *(const float4*)(src + soff + 4);
    uint4 o;
    o.x = pack2(a.x, a.y); o.y = pack2(a.z, a.w);
    o.z = pack2(b.x, b.y); o.w = pack2(b.z, b.w);
    *(uint4*)(dst + doff) = o;
}

// ---------------------------------------------------------------------------
// Mega-kernel: one block per b (256 blocks x 512 thr = 8 waves; wave w owns
// s/q rows [32w, 32w+32)). Heads processed sequentially; og lives ONLY in
// LDS; the out-projection + transpose + add epilogue is fused in. LDS
// 140.5 KB -> 1 block/CU. 16x16x32 bf16 MFMA layouts (verified §3):
//   A/B-frag: row = lane&15, k = (lane>>4)*8 + j
//   C/D:      row = (lane>>4)*4 + reg, col = lane&15
// Per head: phase A projects QKVG (X-frags held in VGPRs, W-frags bf16 from
// ws); phase B: S^T = K·Q^T, softmax over k in registers + shfl_xor(16/32),
// P C-layout -> B-frag via cross-quad shuffles, O^T = V^T·P^T, gated og row
// -> LDS (same wave later consumes it -> no barrier needed for epilogue).
// Epilogue: out[s][b][c] = addt + bo + og[s]·Wo^T, full 128-B-line writes.
// ---------------------------------------------------------------------------
__global__ __launch_bounds__(512, 2) void k_mega(
    const float* __restrict__ X,             // fp32 [B][S][128]
    const unsigned short* __restrict__ Wb,   // bf16 [512][128]
    const float* __restrict__ gbias,         // [128]
    const float* __restrict__ mask,          // [B][S] (k-indexed)
    const float* __restrict__ bias,          // [NH][S][S]
    const unsigned short* __restrict__ Wob,  // bf16 [128][128]
    const float* __restrict__ bo,            // [128]
    const float* __restrict__ addt,          // [S][B][128]
    float* __restrict__ out)                 // [S][B][128]
{
    const int b = blockIdx.x;
    const int t = threadIdx.x;
    const int w = t >> 6, lane = t & 63, l15 = lane & 15, quad = lane >> 4;

    __shared__ unsigned short Qb[SS * 40];    // [s][c] stride 40   (20.5 KB)
    __shared__ unsigned short Kb[SS * 40];    //                    (20.5 KB)
    __shared__ unsigned short Vt[32 * 264];   // [c][s] stride 264  (16.9 KB)
    __shared__ unsigned short Gb[SS * 34];    // [s][c] stride 34   (17.4 KB)
    __shared__ unsigned short OgL[SS * 132];  // [s][f] stride 132  (67.6 KB)
    __shared__ float maskLds[SS];             //                    (1 KB)

    if (t < SS) maskLds[t] = (mask[b * SS + t] - 1.0f) * 1e9f;

    const float qscale = 0.17677669529663687f;  // 1/sqrt(32)

    // X rows for this wave, fp32 -> bf16 A-frags, held across all heads.
    bfrag Xfr[2][4];
#pragma unroll
    for (int st = 0; st < 2; ++st) {
        const int s = w * 32 + st * 16 + l15;
#pragma unroll
        for (int cc = 0; cc < 4; ++cc) {
            const float* p = X + (b * SS + s) * 128 + cc * 32 + quad * 8;
            Xfr[st][cc] = pack_frag(*(const float4*)p, *(const float4*)(p + 4));
        }
    }

    const int srcA = l15 + ((quad & 1) * 2) * 16;
    const int srcB = srcA + 16;
    const bool hi = (quad >> 1) != 0;

    for (int h = 0; h < NH; ++h) {
        __syncthreads();   // prior phase B readers done before we overwrite

        // ---------------- phase A: QKVG projection for head h ------------
        for (int half = 0; half < 2; ++half) {
            bfrag Wfr[4][4];
#pragma unroll
            for (int f4 = 0; f4 < 4; ++f4) {
                const int floc = (half * 4 + f4) * 16 + l15;        // 0..127
                const int grow = (floc >> 5) * 128 + h * 32 + (floc & 31);
#pragma unroll
                for (int cc = 0; cc < 4; ++cc)
                    Wfr[f4][cc] = *(const bfrag*)(Wb + grow * 128 + cc * 32 + quad * 8);
            }
#pragma unroll
            for (int st = 0; st < 2; ++st) {
#pragma unroll
                for (int f4 = 0; f4 < 4; ++f4) {
                    ffrag D = {0.f, 0.f, 0.f, 0.f};
#pragma unroll
                    for (int cc = 0; cc < 4; ++cc)
                        D = __builtin_amdgcn_mfma_f32_16x16x32_bf16(Xfr[st][cc], Wfr[f4][cc], D, 0, 0, 0);
                    const int ft = half * 4 + f4;
                    const int fcol = ft * 16 + l15;
                    const int srow0 = w * 32 + st * 16 + quad * 4;
                    if (ft < 2) {
#pragma unroll
                        for (int r = 0; r < 4; ++r)
                            Qb[(srow0 + r) * 40 + fcol] = f2bf(D[r] * qscale);
                    } else if (ft < 4) {
#pragma unroll
                        for (int r = 0; r < 4; ++r)
                            Kb[(srow0 + r) * 40 + (fcol - 32)] = f2bf(D[r]);
                    } else if (ft < 6) {
                        const int base = (fcol - 64) * 264 + srow0;
                        *(unsigned*)&Vt[base]     = pack2(D[0], D[1]);
                        *(unsigned*)&Vt[base + 2] = pack2(D[2], D[3]);
                    } else {
                        const int c = fcol - 96;
                        const float gb = gbias[h * 32 + c];
#pragma unroll
                        for (int r = 0; r < 4; ++r) {
                            const float g = 1.0f / (1.0f + __expf(-(D[r] + gb)));
                            Gb[(srow0 + r) * 34 + c] = f2bf(g);
                        }
                    }
                }
            }
        }
        __syncthreads();

        // ---------------- phase B: attention for head h -------------------
        for (int qq = 0; qq < 2; ++qq) {
            const int q = w * 32 + qq * 16 + l15;
            const bfrag Qfr = *(const bfrag*)&Qb[q * 40 + quad * 8];

            ffrag S[16];
#pragma unroll
            for (int kt = 0; kt < 16; ++kt) {
                const bfrag Kfr = *(const bfrag*)&Kb[(kt * 16 + l15) * 40 + quad * 8];
                const ffrag z = {0.f, 0.f, 0.f, 0.f};
                S[kt] = __builtin_amdgcn_mfma_f32_16x16x32_bf16(Kfr, Qfr, z, 0, 0, 0);
            }

            const float* brow = bias + (h * SS + q) * SS;
            float m = -1e30f;
#pragma unroll
            for (int kt = 0; kt < 16; ++kt) {
                const float4 bv = *(const float4*)(brow + kt * 16 + quad * 4);
                const float4 mv = *(const float4*)(maskLds + kt * 16 + quad * 4);
                S[kt][0] += bv.x + mv.x; S[kt][1] += bv.y + mv.y;
                S[kt][2] += bv.z + mv.z; S[kt][3] += bv.w + mv.w;
                m = fmaxf(m, fmaxf(fmaxf(S[kt][0], S[kt][1]), fmaxf(S[kt][2], S[kt][3])));
            }
            m = fmaxf(m, __shfl_xor(m, 16, 64));
            m = fmaxf(m, __shfl_xor(m, 32, 64));

            float l = 0.f;
            unsigned pk[16][2];   // P bf16 pairs (r01, r23), C-layout
#pragma unroll
            for (int kt = 0; kt < 16; ++kt) {
                const float p0 = __expf(S[kt][0] - m);
                const float p1 = __expf(S[kt][1] - m);
                const float p2 = __expf(S[kt][2] - m);
                const float p3 = __expf(S[kt][3] - m);
                l += (p0 + p1) + (p2 + p3);
                pk[kt][0] = pack2(p0, p1);
                pk[kt][1] = pack2(p2, p3);
            }
            l += __shfl_xor(l, 16, 64);
            l += __shfl_xor(l, 32, 64);

            // C-layout -> B-frag via cross-quad shuffles; V A-frags in-loop.
            ffrag O[2];
            O[0] = (ffrag){0.f, 0.f, 0.f, 0.f};
            O[1] = (ffrag){0.f, 0.f, 0.f, 0.f};
#pragma unroll
            for (int ck = 0; ck < 8; ++ck) {
                const unsigned a0 = (unsigned)__shfl((int)pk[2 * ck][0],     srcA, 64);
                const unsigned b0 = (unsigned)__shfl((int)pk[2 * ck + 1][0], srcA, 64);
                const unsigned a1 = (unsigned)__shfl((int)pk[2 * ck][1],     srcA, 64);
                const unsigned b1 = (unsigned)__shfl((int)pk[2 * ck + 1][1], srcA, 64);
                const unsigned a2 = (unsigned)__shfl((int)pk[2 * ck][0],     srcB, 64);
                const unsigned b2 = (unsigned)__shfl((int)pk[2 * ck + 1][0], srcB, 64);
                const unsigned a3 = (unsigned)__shfl((int)pk[2 * ck][1],     srcB, 64);
                const unsigned b3 = (unsigned)__shfl((int)pk[2 * ck + 1][1], srcB, 64);
                FragU fu;
                fu.u[0] = hi ? b0 : a0;
                fu.u[1] = hi ? b1 : a1;
                fu.u[2] = hi ? b2 : a2;
                fu.u[3] = hi ? b3 : a3;
                const bfrag V0 = *(const bfrag*)&Vt[l15 * 264 + ck * 32 + quad * 8];
                const bfrag V1 = *(const bfrag*)&Vt[(16 + l15) * 264 + ck * 32 + quad * 8];
                O[0] = __builtin_amdgcn_mfma_f32_16x16x32_bf16(V0, fu.b, O[0], 0, 0, 0);
                O[1] = __builtin_amdgcn_mfma_f32_16x16x32_bf16(V1, fu.b, O[1], 0, 0, 0);
            }

            const float invl = 1.0f / l;
            const unsigned short* gr = &Gb[q * 34];
            unsigned* orow = (unsigned*)&OgL[q * 132 + h * 32];
#pragma unroll
            for (int ch = 0; ch < 2; ++ch) {
                const int c0 = ch * 16 + quad * 4;
                const float v0 = O[ch][0] * invl * bf2f(gr[c0 + 0]);
                const float v1 = O[ch][1] * invl * bf2f(gr[c0 + 1]);
                const float v2 = O[ch][2] * invl * bf2f(gr[c0 + 2]);
                const float v3 = O[ch][3] * invl * bf2f(gr[c0 + 3]);
                orow[(c0 >> 1) + 0] = pack2(v0, v1);
                orow[(c0 >> 1) + 1] = pack2(v2, v3);
            }
        }
    }

    // ---------------- epilogue: out-proj + transpose + add ----------------
    // Wave w's og rows were written by wave w itself -> no barrier needed.
#pragma unroll
    for (int st = 0; st < 2; ++st) {
        bfrag Ab[4];
#pragma unroll
        for (int cc = 0; cc < 4; ++cc)
            Ab[cc] = *(const bfrag*)&OgL[(w * 32 + st * 16 + l15) * 132 + cc * 32 + quad * 8];

#pragma unroll
        for (int ct = 0; ct < 8; ++ct) {
            ffrag D = {0.f, 0.f, 0.f, 0.f};
#pragma unroll
            for (int cc = 0; cc < 4; ++cc) {
                const bfrag Bf = *(const bfrag*)(Wob + (ct * 16 + l15) * 128 + cc * 32 + quad * 8);
                D = __builtin_amdgcn_mfma_f32_16x16x32_bf16(Ab[cc], Bf, D, 0, 0, 0);
            }
            const float bov = bo[ct * 16 + l15];
#pragma unroll
            for (int r = 0; r < 4; ++r) {
                const int s = w * 32 + st * 16 + quad * 4 + r;
                const size_t idx = ((size_t)s * BB + b) * 128 + ct * 16 + l15;
                out[idx] = D[r] + bov + addt[idx];
            }
        }
    }
}

extern "C" void kernel_launch(void* const* d_in, const int* in_sizes, int n_in,
                              void* d_out, int out_size, void* d_ws, size_t ws_size,
                              hipStream_t stream) {
    const float* X     = (const float*)d_in[0];  // input_qkv [1,256,256,128]
    const float* mask  = (const float*)d_in[1];  // [1,256,1,1,256]
    const float* bias  = (const float*)d_in[2];  // [1,1,4,256,256]
    const float* addt  = (const float*)d_in[3];  // [1,256,256,128]
    const float* Wqkvg = (const float*)d_in[4];  // [512,128]
    const float* gbias = (const float*)d_in[5];  // [128]
    const float* Wo    = (const float*)d_in[6];  // [128,128]
    const float* bo    = (const float*)d_in[7];  // [128]
    float* out = (float*)d_out;

    unsigned short* ws  = (unsigned short*)d_ws;
    unsigned short* Wb  = ws + WB_OFF;
    unsigned short* Wob = ws + WOB_OFF;

    k0_cast<<<40, 256, 0, stream>>>(Wqkvg, Wo, ws);
    k_mega<<<BB, 512, 0, stream>>>(X, Wb, gbias, mask, bias, Wob, bo, addt, out);
}

// Round 7
// 279.576 us; speedup vs baseline: 1.0232x; 1.0232x over previous
//
#include <hip/hip_runtime.h>
#include <math.h>

#define BB 256
#define SS 256
#define NH 4

typedef __attribute__((ext_vector_type(8))) short bfrag;   // 8 bf16 (4 VGPRs)
typedef __attribute__((ext_vector_type(4))) float ffrag;   // 4 fp32 acc

__device__ inline unsigned short f2bf(float x) {
    unsigned u = __float_as_uint(x);
    u += 0x7FFF + ((u >> 16) & 1);          // round-to-nearest-even
    return (unsigned short)(u >> 16);
}
__device__ inline float bf2f(unsigned short h) {
    return __uint_as_float(((unsigned)h) << 16);
}
__device__ inline unsigned pack2(float a, float b) {
    return (unsigned)f2bf(a) | ((unsigned)f2bf(b) << 16);
}
__device__ inline bfrag pack_frag(float4 a, float4 b) {
    bfrag f;
    f[0] = (short)f2bf(a.x); f[1] = (short)f2bf(a.y);
    f[2] = (short)f2bf(a.z); f[3] = (short)f2bf(a.w);
    f[4] = (short)f2bf(b.x); f[5] = (short)f2bf(b.y);
    f[6] = (short)f2bf(b.z); f[7] = (short)f2bf(b.w);
    return f;
}
union FragU { unsigned u[4]; bfrag b; };

// ws layout (bf16 elements): Wb [512][128] at 0, Wob [128][128] at 65536.
#define WB_OFF  0
#define WOB_OFF 65536

// ---------------------------------------------------------------------------
// k0: cast W_qkvg + W_o fp32 -> bf16. 81920 elems, 8/thread, 40 blocks.
// ---------------------------------------------------------------------------
__global__ __launch_bounds__(256) void k0_cast(
    const float* __restrict__ W, const float* __restrict__ Wo,
    unsigned short* __restrict__ dst)
{
    const int gid = blockIdx.x * 256 + threadIdx.x;
    const int WN8 = 65536 / 8, WoN8 = 16384 / 8;
    const float* src;
    size_t soff, doff;
    if (gid < WN8)            { src = W;  soff = (size_t)gid * 8;         doff = WB_OFF + soff; }
    else if (gid < WN8 + WoN8) { src = Wo; soff = (size_t)(gid - WN8) * 8; doff = WOB_OFF + soff; }
    else return;
    const float4 a = *(const float4*)(src + soff);
    const float4 b = *(const float4*)(src + soff + 4);
    uint4 o;
    o.x = pack2(a.x, a.y); o.y = pack2(a.z, a.w);
    o.z = pack2(b.x, b.y); o.w = pack2(b.z, b.w);
    *(uint4*)(dst + doff) = o;
}

// ---------------------------------------------------------------------------
// Mega-kernel: one block per b (256 blocks x 512 thr = 8 waves; wave w owns
// s/q rows [32w, 32w+32)). Heads sequential; og only in LDS; out-projection
// fused. LDS 143,872 B -> 1 block/CU.
// The Qb/Kb/Vt/Gb region (75.3 KB) is UNIONED with the epilogue's fp32
// staging tile (67.6 KB): after phase B of the last head (one barrier), each
// wave stages D+bo rows in LDS, then writes out/reads addt as FULL 128-B
// lines (32 lanes x float4 = one contiguous 512-B row). Round-6 evidence:
// the previous C-layout direct store (64-B per row per instr) caused 4x
// write amplification (WRITE_SIZE 133.7 MB for a 33.5 MB output) via
// partial-line L2 evictions + RMW fetches.
// 16x16x32 bf16 MFMA layouts (verified §3):
//   A/B-frag: row = lane&15, k = (lane>>4)*8 + j
//   C/D:      row = (lane>>4)*4 + reg, col = lane&15
// ---------------------------------------------------------------------------
__global__ __launch_bounds__(512, 2) void k_mega(
    const float* __restrict__ X,             // fp32 [B][S][128]
    const unsigned short* __restrict__ Wb,   // bf16 [512][128]
    const float* __restrict__ gbias,         // [128]
    const float* __restrict__ mask,          // [B][S] (k-indexed)
    const float* __restrict__ bias,          // [NH][S][S]
    const unsigned short* __restrict__ Wob,  // bf16 [128][128]
    const float* __restrict__ bo,            // [128]
    const float* __restrict__ addt,          // [S][B][128]
    float* __restrict__ out)                 // [S][B][128]
{
    const int b = blockIdx.x;
    const int t = threadIdx.x;
    const int w = t >> 6, lane = t & 63, l15 = lane & 15, quad = lane >> 4;

    // Region A: attention buffers, reused as epilogue staging (75,264 B).
    __shared__ __align__(16) unsigned char smemA[75264];
    unsigned short* Qb = (unsigned short*)smemA;   // [s][c] stride 40 (20.5 KB)
    unsigned short* Kb = Qb + SS * 40;             // [s][c] stride 40 (20.5 KB)
    unsigned short* Vt = Kb + SS * 40;             // [c][s] stride 264 (16.9 KB)
    unsigned short* Gb = Vt + 32 * 264;            // [s][c] stride 34 (17.4 KB)

    __shared__ unsigned short OgL[SS * 132];  // [s][f] stride 132  (67.6 KB)
    __shared__ float maskLds[SS];             //                    (1 KB)

    if (t < SS) maskLds[t] = (mask[b * SS + t] - 1.0f) * 1e9f;

    const float qscale = 0.17677669529663687f;  // 1/sqrt(32)

    // X rows for this wave, fp32 -> bf16 A-frags, held across all heads.
    bfrag Xfr[2][4];
#pragma unroll
    for (int st = 0; st < 2; ++st) {
        const int s = w * 32 + st * 16 + l15;
#pragma unroll
        for (int cc = 0; cc < 4; ++cc) {
            const float* p = X + (b * SS + s) * 128 + cc * 32 + quad * 8;
            Xfr[st][cc] = pack_frag(*(const float4*)p, *(const float4*)(p + 4));
        }
    }

    const int srcA = l15 + ((quad & 1) * 2) * 16;
    const int srcB = srcA + 16;
    const bool hi = (quad >> 1) != 0;

    for (int h = 0; h < NH; ++h) {
        __syncthreads();   // prior phase B readers done before we overwrite

        // ---------------- phase A: QKVG projection for head h ------------
        for (int half = 0; half < 2; ++half) {
            bfrag Wfr[4][4];
#pragma unroll
            for (int f4 = 0; f4 < 4; ++f4) {
                const int floc = (half * 4 + f4) * 16 + l15;        // 0..127
                const int grow = (floc >> 5) * 128 + h * 32 + (floc & 31);
#pragma unroll
                for (int cc = 0; cc < 4; ++cc)
                    Wfr[f4][cc] = *(const bfrag*)(Wb + grow * 128 + cc * 32 + quad * 8);
            }
#pragma unroll
            for (int st = 0; st < 2; ++st) {
#pragma unroll
                for (int f4 = 0; f4 < 4; ++f4) {
                    ffrag D = {0.f, 0.f, 0.f, 0.f};
#pragma unroll
                    for (int cc = 0; cc < 4; ++cc)
                        D = __builtin_amdgcn_mfma_f32_16x16x32_bf16(Xfr[st][cc], Wfr[f4][cc], D, 0, 0, 0);
                    const int ft = half * 4 + f4;
                    const int fcol = ft * 16 + l15;
                    const int srow0 = w * 32 + st * 16 + quad * 4;
                    if (ft < 2) {
#pragma unroll
                        for (int r = 0; r < 4; ++r)
                            Qb[(srow0 + r) * 40 + fcol] = f2bf(D[r] * qscale);
                    } else if (ft < 4) {
#pragma unroll
                        for (int r = 0; r < 4; ++r)
                            Kb[(srow0 + r) * 40 + (fcol - 32)] = f2bf(D[r]);
                    } else if (ft < 6) {
                        const int base = (fcol - 64) * 264 + srow0;
                        *(unsigned*)&Vt[base]     = pack2(D[0], D[1]);
                        *(unsigned*)&Vt[base + 2] = pack2(D[2], D[3]);
                    } else {
                        const int c = fcol - 96;
                        const float gb = gbias[h * 32 + c];
#pragma unroll
                        for (int r = 0; r < 4; ++r) {
                            const float g = 1.0f / (1.0f + __expf(-(D[r] + gb)));
                            Gb[(srow0 + r) * 34 + c] = f2bf(g);
                        }
                    }
                }
            }
        }
        __syncthreads();

        // ---------------- phase B: attention for head h -------------------
        for (int qq = 0; qq < 2; ++qq) {
            const int q = w * 32 + qq * 16 + l15;
            const bfrag Qfr = *(const bfrag*)&Qb[q * 40 + quad * 8];

            ffrag S[16];
#pragma unroll
            for (int kt = 0; kt < 16; ++kt) {
                const bfrag Kfr = *(const bfrag*)&Kb[(kt * 16 + l15) * 40 + quad * 8];
                const ffrag z = {0.f, 0.f, 0.f, 0.f};
                S[kt] = __builtin_amdgcn_mfma_f32_16x16x32_bf16(Kfr, Qfr, z, 0, 0, 0);
            }

            const float* brow = bias + (h * SS + q) * SS;
            float m = -1e30f;
#pragma unroll
            for (int kt = 0; kt < 16; ++kt) {
                const float4 bv = *(const float4*)(brow + kt * 16 + quad * 4);
                const float4 mv = *(const float4*)(maskLds + kt * 16 + quad * 4);
                S[kt][0] += bv.x + mv.x; S[kt][1] += bv.y + mv.y;
                S[kt][2] += bv.z + mv.z; S[kt][3] += bv.w + mv.w;
                m = fmaxf(m, fmaxf(fmaxf(S[kt][0], S[kt][1]), fmaxf(S[kt][2], S[kt][3])));
            }
            m = fmaxf(m, __shfl_xor(m, 16, 64));
            m = fmaxf(m, __shfl_xor(m, 32, 64));

            float l = 0.f;
            unsigned pk[16][2];   // P bf16 pairs (r01, r23), C-layout
#pragma unroll
            for (int kt = 0; kt < 16; ++kt) {
                const float p0 = __expf(S[kt][0] - m);
                const float p1 = __expf(S[kt][1] - m);
                const float p2 = __expf(S[kt][2] - m);
                const float p3 = __expf(S[kt][3] - m);
                l += (p0 + p1) + (p2 + p3);
                pk[kt][0] = pack2(p0, p1);
                pk[kt][1] = pack2(p2, p3);
            }
            l += __shfl_xor(l, 16, 64);
            l += __shfl_xor(l, 32, 64);

            // C-layout -> B-frag via cross-quad shuffles; V A-frags in-loop.
            ffrag O[2];
            O[0] = (ffrag){0.f, 0.f, 0.f, 0.f};
            O[1] = (ffrag){0.f, 0.f, 0.f, 0.f};
#pragma unroll
            for (int ck = 0; ck < 8; ++ck) {
                const unsigned a0 = (unsigned)__shfl((int)pk[2 * ck][0],     srcA, 64);
                const unsigned b0 = (unsigned)__shfl((int)pk[2 * ck + 1][0], srcA, 64);
                const unsigned a1 = (unsigned)__shfl((int)pk[2 * ck][1],     srcA, 64);
                const unsigned b1 = (unsigned)__shfl((int)pk[2 * ck + 1][1], srcA, 64);
                const unsigned a2 = (unsigned)__shfl((int)pk[2 * ck][0],     srcB, 64);
                const unsigned b2 = (unsigned)__shfl((int)pk[2 * ck + 1][0], srcB, 64);
                const unsigned a3 = (unsigned)__shfl((int)pk[2 * ck][1],     srcB, 64);
                const unsigned b3 = (unsigned)__shfl((int)pk[2 * ck + 1][1], srcB, 64);
                FragU fu;
                fu.u[0] = hi ? b0 : a0;
                fu.u[1] = hi ? b1 : a1;
                fu.u[2] = hi ? b2 : a2;
                fu.u[3] = hi ? b3 : a3;
                const bfrag V0 = *(const bfrag*)&Vt[l15 * 264 + ck * 32 + quad * 8];
                const bfrag V1 = *(const bfrag*)&Vt[(16 + l15) * 264 + ck * 32 + quad * 8];
                O[0] = __builtin_amdgcn_mfma_f32_16x16x32_bf16(V0, fu.b, O[0], 0, 0, 0);
                O[1] = __builtin_amdgcn_mfma_f32_16x16x32_bf16(V1, fu.b, O[1], 0, 0, 0);
            }

            const float invl = 1.0f / l;
            const unsigned short* gr = &Gb[q * 34];
            unsigned* orow = (unsigned*)&OgL[q * 132 + h * 32];
#pragma unroll
            for (int ch = 0; ch < 2; ++ch) {
                const int c0 = ch * 16 + quad * 4;
                const float v0 = O[ch][0] * invl * bf2f(gr[c0 + 0]);
                const float v1 = O[ch][1] * invl * bf2f(gr[c0 + 1]);
                const float v2 = O[ch][2] * invl * bf2f(gr[c0 + 2]);
                const float v3 = O[ch][3] * invl * bf2f(gr[c0 + 3]);
                orow[(c0 >> 1) + 0] = pack2(v0, v1);
                orow[(c0 >> 1) + 1] = pack2(v2, v3);
            }
        }
    }

    // ---------------- epilogue: out-proj + transpose + add ----------------
    __syncthreads();   // all waves done reading Qb/Kb/Vt/Gb -> reuse as SW

    float* SW = (float*)smemA + (size_t)w * (16 * 132);  // per-wave 16 rows
    float bov[8];
#pragma unroll
    for (int ct = 0; ct < 8; ++ct) bov[ct] = bo[ct * 16 + l15];

#pragma unroll
    for (int st = 0; st < 2; ++st) {
        bfrag Ab[4];
#pragma unroll
        for (int cc = 0; cc < 4; ++cc)
            Ab[cc] = *(const bfrag*)&OgL[(w * 32 + st * 16 + l15) * 132 + cc * 32 + quad * 8];

        // D = og · Wo^T + bo -> stage in LDS (C-layout scatter, 2-way conflict)
#pragma unroll
        for (int ct = 0; ct < 8; ++ct) {
            ffrag D = {0.f, 0.f, 0.f, 0.f};
#pragma unroll
            for (int cc = 0; cc < 4; ++cc) {
                const bfrag Bf = *(const bfrag*)(Wob + (ct * 16 + l15) * 128 + cc * 32 + quad * 8);
                D = __builtin_amdgcn_mfma_f32_16x16x32_bf16(Ab[cc], Bf, D, 0, 0, 0);
            }
#pragma unroll
            for (int r = 0; r < 4; ++r)
                SW[(quad * 4 + r) * 132 + ct * 16 + l15] = D[r] + bov[ct];
        }

        // full-line writeback: 32 lanes cover one 512-B row; addt read same
#pragma unroll
        for (int it = 0; it < 8; ++it) {
            const int rl = it * 2 + (lane >> 5);         // local row 0..15
            const int s = w * 32 + st * 16 + rl;
            const int c4 = (lane & 31) * 4;
            float4 v = *(const float4*)&SW[rl * 132 + c4];
            const size_t idx = ((size_t)s * BB + b) * 128 + c4;
            const float4 a = *(const float4*)(addt + idx);
            v.x += a.x; v.y += a.y; v.z += a.z; v.w += a.w;
            *(float4*)(out + idx) = v;
        }
    }
}

extern "C" void kernel_launch(void* const* d_in, const int* in_sizes, int n_in,
                              void* d_out, int out_size, void* d_ws, size_t ws_size,
                              hipStream_t stream) {
    const float* X     = (const float*)d_in[0];  // input_qkv [1,256,256,128]
    const float* mask  = (const float*)d_in[1];  // [1,256,1,1,256]
    const float* bias  = (const float*)d_in[2];  // [1,1,4,256,256]
    const float* addt  = (const float*)d_in[3];  // [1,256,256,128]
    const float* Wqkvg = (const float*)d_in[4];  // [512,128]
    const float* gbias = (const float*)d_in[5];  // [128]
    const float* Wo    = (const float*)d_in[6];  // [128,128]
    const float* bo    = (const float*)d_in[7];  // [128]
    float* out = (float*)d_out;

    unsigned short* ws  = (unsigned short*)d_ws;
    unsigned short* Wb  = ws + WB_OFF;
    unsigned short* Wob = ws + WOB_OFF;

    k0_cast<<<40, 256, 0, stream>>>(Wqkvg, Wo, ws);
    k_mega<<<BB, 512, 0, stream>>>(X, Wb, gbias, mask, bias, Wob, bo, addt, out);
}